// Round 15
// baseline (302.265 us; speedup 1.0000x reference)
//
#include <hip/hip_runtime.h>
#include <math.h>

#define HP 265
#define NPIX 70225        // 265*265
#define ROWF 8480         // HP*32 elements per (b,h) row, channels-last
#define TWO_PI 6.28318530717958647692f

// ws layout (float offsets); xb/A16/weights/twiddle-mats are bf16 (ushort)
#define OFF_X     0            // [8][265][265][32] ushort  = 8,988,800 slots
#define OFF_U     8988800      // [8][26][8480] f32         = 1,763,840
#define OFF_G     10752640     // [4][8][32][24][12] cplx   =   589,824
#define OFF_A     11342464     // [8][265][32][32] ushort   = 1,085,440 slots
#define OFF_TFB   12427904     // [32][288] ushort          =     4,608 slots
#define OFF_TS    12432512     // [272][32] ushort          =     4,352 slots
#define OFF_W1B   12436864     // [128][32] ushort          =     2,048 slots
#define OFF_W2B   12438912     // [16][128] ushort          =     1,024 slots
#define OFF_PWB   12439936     // [4][32][32] ushort        =     2,048 slots

typedef __attribute__((ext_vector_type(8))) short short8;
typedef __attribute__((ext_vector_type(4))) float f32x4;

// tanh-form GELU: x*sigmoid(1.59577x + 0.071355x^3); max |diff vs erf-gelu| ~3e-4
__device__ __forceinline__ float gelu_f(float v){
  float x2 = v*v;
  float p  = fmaf(x2, 0.10295597f, 2.30212056f);
  float tn = -v*p;
  float e  = __builtin_amdgcn_exp2f(tn);
  float r  = __builtin_amdgcn_rcpf(1.0f + e);
  return v * r;
}
__device__ __forceinline__ unsigned short f2b(float f){
  unsigned u = __float_as_uint(f);
  u += 0x7FFFu + ((u >> 16) & 1u);
  return (unsigned short)(u >> 16);
}
// HW pair convert: dst[15:0]=bf16(lo), dst[31:16]=bf16(hi), RNE
__device__ __forceinline__ unsigned cvtpk(float lo, float hi){
  unsigned r;
  asm("v_cvt_pk_bf16_f32 %0, %1, %2" : "=v"(r) : "v"(lo), "v"(hi));
  return r;
}

__device__ __forceinline__ void init_body(int idx,
                       unsigned short* __restrict__ Tfb, unsigned short* __restrict__ Ts,
                       unsigned short* __restrict__ w1b, unsigned short* __restrict__ w2b,
                       unsigned short* __restrict__ pwb,
                       const float* __restrict__ fc1w, const float* __restrict__ fc2w,
                       const float* __restrict__ pw_w){
  if (idx < 32*288){                    // analysis twiddles: row 2k=cos, 2k+1=-sin
    int m = idx / 288, hc = idx % 288;
    unsigned short v = 0;
    if (m < 26 && hc < 265){
      int k = m >> 1;
      int t = (hc*k) % HP;
      float s, c; sincosf(TWO_PI*(float)t/(float)HP, &s, &c);
      v = f2b((m & 1) ? -s : c);
    }
    Tfb[idx] = v;
  }
  if (idx < 272*32){                    // synthesis twiddles (invN folded)
    int w = idx >> 5, kap = idx & 31;
    unsigned short v = 0;
    if (w < HP && kap < 24){
      int k = kap >> 1;
      int t = (w*k) % HP;
      float s, c; sincosf(TWO_PI*(float)t/(float)HP, &s, &c);
      const float invN = 1.f/70225.f;
      float val = (!(kap&1)) ? invN*(k==0 ? 1.f : 2.f*c)
                             : ((k==0) ? 0.f : -invN*2.f*s);
      v = f2b(val);
    }
    Ts[idx] = v;
  }
  if (idx < 4096){                      // w1b[n*32+k] = fc1w[k*128+n]
    int n = idx >> 5, k = idx & 31;
    w1b[idx] = f2b(fc1w[k*128 + n]);
  }
  if (idx < 2048){                      // w2b[n*128+k] = fc2w[k*3+n], n<3 else 0
    int n = idx >> 7, k = idx & 127;
    w2b[idx] = (n < 3) ? f2b(fc2w[k*3 + n]) : (unsigned short)0;
  }
  if (idx < 4096)                       // pwb = pw_w bf16
    pwb[idx] = f2b(pw_w[idx]);
}

// fc0 (3->32, bf16 channels-last, zero pad) + copy x_en/x_de + fused init tail
__global__ __launch_bounds__(256) void k_fc0(const float* __restrict__ xen,
                                             const float* __restrict__ w0,
                                             const float* __restrict__ b0,
                                             unsigned short* __restrict__ xb,
                                             float* __restrict__ out,
                                             unsigned short* __restrict__ Tfb,
                                             unsigned short* __restrict__ Ts,
                                             unsigned short* __restrict__ w1b,
                                             unsigned short* __restrict__ w2b,
                                             unsigned short* __restrict__ pwb,
                                             const float* __restrict__ fc1w,
                                             const float* __restrict__ fc2w,
                                             const float* __restrict__ pw_w){
  if (blockIdx.x >= 2195){
    init_body((blockIdx.x - 2195)*256 + threadIdx.x, Tfb, Ts, w1b, w2b, pwb,
              fc1w, fc2w, pw_w);
    return;
  }
  int idx = blockIdx.x*256 + threadIdx.x;
  if (idx >= 8*NPIX) return;
  int w = idx % HP; int t = idx / HP; int h = t % HP; int b = t / HP;
  float o32[32];
  if (h < 256 && w < 256){
    const float* xp = xen + (((size_t)b*3)*256 + h)*256 + w;
    float c0 = xp[0], c1 = xp[65536], c2 = xp[131072];
    #pragma unroll
    for (int d = 0; d < 32; ++d)
      o32[d] = b0[d] + c0*w0[d] + c1*w0[32+d] + c2*w0[64+d];
    size_t be = ((size_t)b*3)*65536 + (h<<8) + w;
    out[1769472 + be]          = c0;
    out[1769472 + be + 65536]  = c1;
    out[1769472 + be + 131072] = c2;
    if (((h|w)&3) == 0){
      size_t db = ((size_t)b*3)*4096 + ((h>>2)<<6) + (w>>2);
      out[98304 + db]        = c0;
      out[98304 + db + 4096] = c1;
      out[98304 + db + 8192] = c2;
    }
  } else {
    #pragma unroll
    for (int d = 0; d < 32; ++d) o32[d] = 0.f;
  }
  uint4* dst = (uint4*)(xb + (size_t)idx*32);
  #pragma unroll
  for (int q = 0; q < 4; ++q)
    dst[q] = make_uint4(cvtpk(o32[8*q],o32[8*q+1]),   cvtpk(o32[8*q+2],o32[8*q+3]),
                        cvtpk(o32[8*q+4],o32[8*q+5]), cvtpk(o32[8*q+6],o32[8*q+7]));
}

// MFMA h-DFT, LDS-free: U[b][m<26][n] = sum_h Tfb[m][h] * x[b][h][n]
__global__ __launch_bounds__(256) void k_dftm(const unsigned short* __restrict__ xb,
                                              const unsigned short* __restrict__ Tfb,
                                              float* __restrict__ U32){
  int tid = threadIdx.x;
  int wv = tid>>6, lane = tid&63, lr = lane&15, g = lane>>4, lk = g*8;
  int n0 = blockIdx.x*64;
  int b  = blockIdx.y;
  int n  = n0 + wv*16 + lr;
  const unsigned short* xcol = xb + (size_t)b*HP*ROWF + n;
  f32x4 acc0 = {0.f,0.f,0.f,0.f}, acc1 = {0.f,0.f,0.f,0.f};
  #pragma unroll
  for (int kc = 0; kc < 9; ++kc){
    short8 hv;
    int hb = kc*32 + lk;
    #pragma unroll
    for (int q = 0; q < 8; ++q){
      int h = hb + q;
      hv[q] = (h < HP) ? (short)xcol[(size_t)h*ROWF] : (short)0;
    }
    short8 aT0 = *(const short8*)&Tfb[lr*288 + kc*32 + lk];
    short8 aT1 = *(const short8*)&Tfb[(16+lr)*288 + kc*32 + lk];
    acc0 = __builtin_amdgcn_mfma_f32_16x16x32_bf16(aT0, hv, acc0, 0,0,0);
    acc1 = __builtin_amdgcn_mfma_f32_16x16x32_bf16(aT1, hv, acc1, 0,0,0);
  }
  if (n < 8480){
    #pragma unroll
    for (int r = 0; r < 4; ++r){
      int m0 = g*4 + r;
      U32[((size_t)b*26 + m0)*8480 + n] = acc0[r];
      int m1 = 16 + m0;
      if (m1 < 26) U32[((size_t)b*26 + m1)*8480 + n] = acc1[r];
    }
  }
}

// Column DFT + mode mix, one block per (j, b, ws); ws splits w-sweep in 4
__global__ __launch_bounds__(256) void k_spec(const float* __restrict__ U32,
                                              const float* __restrict__ w1r,
                                              const float* __restrict__ w1i,
                                              const float* __restrict__ w2r,
                                              const float* __restrict__ w2i,
                                              float2* __restrict__ G, int l){
  __shared__ float part[256*25];
  __shared__ float Xs[32*25];
  int j = blockIdx.x;
  int b = blockIdx.y;
  int ws = blockIdx.z;
  int tid = threadIdx.x;
  int wsub = tid >> 5, i = tid & 31;
  int kk   = (j < 12) ? j : (24 - j);
  bool cj  = (j >= 12);
  float xr[12], xi[12];
  #pragma unroll
  for (int k = 0; k < 12; ++k){ xr[k] = 0.f; xi[k] = 0.f; }
  const float* ubr = U32 + ((size_t)(b*26 + 2*kk))*8480;
  for (int w = ws*8 + wsub; w < HP; w += 32){
    int n = w*32 + i;
    float ux = ubr[n];
    float uy = ubr[8480 + n];
    if (cj) uy = -uy;
    float bs, bc; sincosf(-TWO_PI*(float)w/(float)HP, &bs, &bc);
    float pr = 1.f, pi = 0.f;
    #pragma unroll
    for (int k = 0; k < 12; ++k){
      xr[k] = fmaf(ux, pr, fmaf(-uy, pi, xr[k]));
      xi[k] = fmaf(ux, pi, fmaf( uy, pr, xi[k]));
      float npr = pr*bc - pi*bs;
      pi = fmaf(pr, bs, pi*bc);
      pr = npr;
    }
  }
  #pragma unroll
  for (int k = 0; k < 12; ++k){
    part[tid*25 + 2*k]     = xr[k];
    part[tid*25 + 2*k + 1] = xi[k];
  }
  __syncthreads();
  {
    int sg = tid >> 5;
    int ii = tid & 31;
    #pragma unroll
    for (int s0 = 0; s0 < 3; ++s0){
      int s = sg*3 + s0;
      float acc = 0.f;
      #pragma unroll
      for (int wq = 0; wq < 8; ++wq) acc += part[(wq*32 + ii)*25 + s];
      Xs[ii*25 + s] = acc;
    }
  }
  __syncthreads();
  int ky = (j < 12) ? j : (j - 12);
  const float* wr = (j < 12) ? w1r : w2r;
  const float* wi = (j < 12) ? w1i : w2i;
  float2* Gp = G + (size_t)ws*73728;
  for (int p = tid; p < 384; p += 256){
    int o = p / 12, kx = p % 12;
    size_t wbase = (size_t)l*147456 + (size_t)o*144 + (size_t)ky*12 + kx;
    float gr = 0.f, gi = 0.f;
    #pragma unroll 4
    for (int i2 = 0; i2 < 32; ++i2){
      float xvr = Xs[i2*25 + 2*kx];
      float xvi = Xs[i2*25 + 2*kx + 1];
      float a = wr[wbase + (size_t)i2*4608];
      float c = wi[wbase + (size_t)i2*4608];
      gr += xvr*a - xvi*c;
      gi += xvr*c + xvi*a;
    }
    Gp[((size_t)(b*32 + o)*24 + j)*12 + kx] = make_float2(gr, gi);
  }
}

// Inverse row synthesis (sums the 4 G partials); writes A as bf16 [b][h][o][32]
__global__ __launch_bounds__(320) void k_idft_h(const float2* __restrict__ G,
                                                unsigned short* __restrict__ A16){
  __shared__ float2 gs[288];
  int bo = blockIdx.x;
  for (int i = threadIdx.x; i < 288; i += 320){
    float2 g0 = G[(size_t)bo*288 + i];
    float2 g1 = G[73728 + (size_t)bo*288 + i];
    float2 g2 = G[2*73728 + (size_t)bo*288 + i];
    float2 g3 = G[3*73728 + (size_t)bo*288 + i];
    gs[i] = make_float2(g0.x+g1.x+g2.x+g3.x, g0.y+g1.y+g2.y+g3.y);
  }
  __syncthreads();
  if (threadIdx.x >= 133) return;
  int h = blockIdx.y*133 + threadIdx.x;
  if (h >= HP) return;
  float ar[12], ai[12];
  #pragma unroll
  for (int k = 0; k < 12; ++k){ ar[k] = 0.f; ai[k] = 0.f; }
  for (int j = 0; j < 24; ++j){
    int ky = (j < 12) ? j : (241 + j);
    int t = (ky*h) % HP;
    float s, c; sincosf(TWO_PI*(float)t/(float)HP, &s, &c);
    #pragma unroll
    for (int k = 0; k < 12; ++k){
      float2 g = gs[j*12 + k];
      ar[k] = fmaf(g.x, c, fmaf(-g.y, s, ar[k]));
      ai[k] = fmaf(g.x, s, fmaf( g.y, c, ai[k]));
    }
  }
  int b = bo >> 5, o = bo & 31;
  uint4* ap = (uint4*)(A16 + (((size_t)(b*HP + h))*32 + o)*32);
  #pragma unroll
  for (int q = 0; q < 3; ++q)
    ap[q] = make_uint4(cvtpk(ar[4*q],   ai[4*q]),   cvtpk(ar[4*q+1], ai[4*q+1]),
                       cvtpk(ar[4*q+2], ai[4*q+2]), cvtpk(ar[4*q+3], ai[4*q+3]));
  ap[3] = make_uint4(0u, 0u, 0u, 0u);
}

// MFMA final, operand-swapped (D[o][w]), w-split over grid.z, manual prefetch:
// next iteration's B-fragments are issued before this iteration's compute.
__global__ __launch_bounds__(256) void k_final(const unsigned short* __restrict__ A16,
                                               const unsigned short* __restrict__ Tsyn,
                                               const unsigned short* __restrict__ pwb,
                                               const float* __restrict__ pw_b,
                                               unsigned short* __restrict__ xb, int l){
  int tid = threadIdx.x;
  int wv = tid>>6, lane = tid&63, lr = lane&15, g = lane>>4, lk = g*8;
  int h = blockIdx.x*4 + wv;
  int b = blockIdx.y;
  int z = blockIdx.z;
  if (h >= HP) return;
  const unsigned short* arow = A16 + (size_t)(b*HP + h)*1024;
  short8 aA0 = *(const short8*)&arow[lr*32 + lk];
  short8 aA1 = *(const short8*)&arow[(16+lr)*32 + lk];
  short8 aP0 = *(const short8*)&pwb[l*1024 + lr*32 + lk];
  short8 aP1 = *(const short8*)&pwb[l*1024 + (16+lr)*32 + lk];
  float4 vb0 = *(const float4*)&pw_b[l*32 + g*4];
  float4 vb1 = *(const float4*)&pw_b[l*32 + 16 + g*4];
  unsigned short* xrow = xb + (size_t)(b*HP + h)*ROWF;
  const f32x4 z4 = {0.f,0.f,0.f,0.f};
  const int wt0 = z ? 9 : 0, wt1 = z ? 17 : 9;
  int w = wt0*16 + lr;
  short8 bT = *(const short8*)&Tsyn[(size_t)w*32 + lk];
  short8 bX = *(const short8*)&xrow[(size_t)w*32 + lk];
  #pragma unroll
  for (int wt = wt0; wt < wt1; ++wt){
    short8 nT, nX;
    if (wt + 1 < wt1){
      int wn = (wt+1)*16 + lr;
      nT = *(const short8*)&Tsyn[(size_t)wn*32 + lk];
      nX = *(const short8*)&xrow[(size_t)wn*32 + lk];
    }
    f32x4 a0 = __builtin_amdgcn_mfma_f32_16x16x32_bf16(aA0, bT, z4, 0,0,0);
    a0 = __builtin_amdgcn_mfma_f32_16x16x32_bf16(aP0, bX, a0, 0,0,0);
    f32x4 a1 = __builtin_amdgcn_mfma_f32_16x16x32_bf16(aA1, bT, z4, 0,0,0);
    a1 = __builtin_amdgcn_mfma_f32_16x16x32_bf16(aP1, bX, a1, 0,0,0);
    if (w < HP){
      float v0[4], v1[4];
      v0[0]=a0[0]+vb0.x; v0[1]=a0[1]+vb0.y; v0[2]=a0[2]+vb0.z; v0[3]=a0[3]+vb0.w;
      v1[0]=a1[0]+vb1.x; v1[1]=a1[1]+vb1.y; v1[2]=a1[2]+vb1.z; v1[3]=a1[3]+vb1.w;
      if (l < 3){
        #pragma unroll
        for (int r = 0; r < 4; ++r){ v0[r] = gelu_f(v0[r]); v1[r] = gelu_f(v1[r]); }
      }
      *(uint2*)&xrow[(size_t)w*32 + g*4] =
          make_uint2(cvtpk(v0[0],v0[1]), cvtpk(v0[2],v0[3]));
      *(uint2*)&xrow[(size_t)w*32 + 16 + g*4] =
          make_uint2(cvtpk(v1[0],v1[1]), cvtpk(v1[2],v1[3]));
    }
    bT = nT; bX = nX; w += 16;
  }
}

// MFMA head: fc1 MFMA -> gelu -> LDS P (bf16) -> fc2 MFMA -> epilogue.
// No inline barriers: compiler orders LDS and pipelines across m-tiles.
__global__ __launch_bounds__(256) void k_head(const unsigned short* __restrict__ xb,
                                              const float* __restrict__ xen,
                                              const unsigned short* __restrict__ w1b,
                                              const float* __restrict__ fc1b,
                                              const unsigned short* __restrict__ w2b,
                                              const float* __restrict__ fc2b,
                                              float* __restrict__ out){
  __shared__ unsigned short Pm[4][2][16*136];
  int tid = threadIdx.x;
  int b = blockIdx.x >> 8, h = blockIdx.x & 255;
  int wv = tid>>6, lane = tid&63, lr = lane&15, g = lane>>4, lk = g*8;
  short8 bf1[8], bf2[4];
  #pragma unroll
  for (int nt = 0; nt < 8; ++nt)
    bf1[nt] = *(const short8*)&w1b[(nt*16+lr)*32 + lk];
  #pragma unroll
  for (int ks = 0; ks < 4; ++ks)
    bf2[ks] = *(const short8*)&w2b[lr*128 + ks*32 + lk];
  float f2c = (lr < 3) ? fc2b[lr] : 0.f;
  const unsigned short* xrow = xb + (size_t)(b*HP + h)*ROWF;
  const f32x4 z4 = {0.f,0.f,0.f,0.f};
  #pragma unroll
  for (int m = 0; m < 4; ++m){
    unsigned short* P = Pm[wv][m & 1];
    int p0 = (wv*4 + m)*16;
    short8 ax = *(const short8*)&xrow[(size_t)(p0 + lr)*32 + lk];
    f32x4 acc[8];
    #pragma unroll
    for (int nt = 0; nt < 8; ++nt)
      acc[nt] = __builtin_amdgcn_mfma_f32_16x16x32_bf16(bf1[nt], ax, z4, 0,0,0);
    #pragma unroll
    for (int nt = 0; nt < 8; ++nt){
      float4 bb = *(const float4*)&fc1b[nt*16 + g*4];
      float h0 = gelu_f(acc[nt][0] + bb.x);
      float h1 = gelu_f(acc[nt][1] + bb.y);
      float h2 = gelu_f(acc[nt][2] + bb.z);
      float h3 = gelu_f(acc[nt][3] + bb.w);
      *(uint2*)&P[lr*136 + nt*16 + g*4] =
          make_uint2(cvtpk(h0,h1), cvtpk(h2,h3));
    }
    f32x4 a2 = z4;
    #pragma unroll
    for (int ks = 0; ks < 4; ++ks){
      short8 ap = *(const short8*)&P[lr*136 + ks*32 + lk];
      a2 = __builtin_amdgcn_mfma_f32_16x16x32_bf16(ap, bf2[ks], a2, 0,0,0);
    }
    if (lr < 3){
      size_t base = ((size_t)(b*3 + lr))*65536 + (h<<8) + p0 + g*4;
      float4 xe = *(const float4*)&xen[base];
      float4 pr;
      pr.x = a2[0] + f2c + xe.x;
      pr.y = a2[1] + f2c + xe.y;
      pr.z = a2[2] + f2c + xe.z;
      pr.w = a2[3] + f2c + xe.w;
      *(float4*)&out[196608 + base] = pr;
      if ((h & 3) == 0){
        int w4 = (p0 + g*4) >> 2;
        out[((size_t)(b*3 + lr))*4096 + ((h>>2)<<6) + w4] = pr.x;
      }
    }
  }
}

extern "C" void kernel_launch(void* const* d_in, const int* in_sizes, int n_in,
                              void* d_out, int out_size, void* d_ws, size_t ws_size,
                              hipStream_t stream){
  const float* x_en  = (const float*)d_in[0];
  const float* fc0_w = (const float*)d_in[2];
  const float* fc0_b = (const float*)d_in[3];
  const float* w1r   = (const float*)d_in[4];
  const float* w1i   = (const float*)d_in[5];
  const float* w2r   = (const float*)d_in[6];
  const float* w2i   = (const float*)d_in[7];
  const float* pw_w  = (const float*)d_in[8];
  const float* pw_b  = (const float*)d_in[9];
  const float* fc1_w = (const float*)d_in[10];
  const float* fc1_b = (const float*)d_in[11];
  const float* fc2_w = (const float*)d_in[12];
  const float* fc2_b = (const float*)d_in[13];
  float* out = (float*)d_out;
  float* ws  = (float*)d_ws;

  unsigned short* xb  = (unsigned short*)(ws + OFF_X);
  float*  U32         = ws + OFF_U;
  float2* G           = (float2*)(ws + OFF_G);
  unsigned short* A16 = (unsigned short*)(ws + OFF_A);
  unsigned short* Tfb = (unsigned short*)(ws + OFF_TFB);
  unsigned short* Ts  = (unsigned short*)(ws + OFF_TS);
  unsigned short* w1b = (unsigned short*)(ws + OFF_W1B);
  unsigned short* w2b = (unsigned short*)(ws + OFF_W2B);
  unsigned short* pwb = (unsigned short*)(ws + OFF_PWB);

  k_fc0<<<2231, 256, 0, stream>>>(x_en, fc0_w, fc0_b, xb, out,
                                  Tfb, Ts, w1b, w2b, pwb, fc1_w, fc2_w, pw_w);
  for (int l = 0; l < 4; ++l){
    k_dftm<<<dim3(133,8), 256, 0, stream>>>(xb, Tfb, U32);
    k_spec<<<dim3(24,8,4), 256, 0, stream>>>(U32, w1r, w1i, w2r, w2i, G, l);
    k_idft_h<<<dim3(256,2), 320, 0, stream>>>(G, A16);
    k_final<<<dim3(67,8,2), 256, 0, stream>>>(A16, Ts, pwb, pw_b, xb, l);
  }
  k_head<<<2048, 256, 0, stream>>>(xb, x_en, w1b, fc1_b, w2b, fc2_b, out);
}

// Round 16
// 282.142 us; speedup vs baseline: 1.0713x; 1.0713x over previous
//
#include <hip/hip_runtime.h>
#include <math.h>

#define HP 265
#define NPIX 70225        // 265*265
#define ROWF 8480         // HP*32 elements per (b,h) row, channels-last
#define TWO_PI 6.28318530717958647692f

// ws layout (float offsets); xb/A16/weights/twiddle-mats are bf16 (ushort)
#define OFF_X     0            // [8][265][265][32] ushort  = 8,988,800 slots
#define OFF_U     8988800      // [8][26][8480] f32         = 1,763,840
#define OFF_G     10752640     // [4][8][32][24][12] cplx   =   589,824
#define OFF_A     11342464     // [8][265][32][32] ushort   = 1,085,440 slots
#define OFF_TFB   12427904     // [32][288] ushort          =     4,608 slots
#define OFF_TS    12432512     // [272][32] ushort          =     4,352 slots
#define OFF_W1B   12436864     // [128][32] ushort (pi-permuted) = 2,048 slots
#define OFF_W2B   12438912     // [16][128] ushort          =     1,024 slots
#define OFF_PWB   12439936     // [4][32][32] ushort        =     2,048 slots

typedef __attribute__((ext_vector_type(8))) short short8;
typedef __attribute__((ext_vector_type(4))) float f32x4;

// tanh-form GELU: x*sigmoid(1.59577x + 0.071355x^3); max |diff vs erf-gelu| ~3e-4
__device__ __forceinline__ float gelu_f(float v){
  float x2 = v*v;
  float p  = fmaf(x2, 0.10295597f, 2.30212056f);
  float tn = -v*p;
  float e  = __builtin_amdgcn_exp2f(tn);
  float r  = __builtin_amdgcn_rcpf(1.0f + e);
  return v * r;
}
__device__ __forceinline__ unsigned short f2b(float f){
  unsigned u = __float_as_uint(f);
  u += 0x7FFFu + ((u >> 16) & 1u);
  return (unsigned short)(u >> 16);
}
// HW pair convert: dst[15:0]=bf16(lo), dst[31:16]=bf16(hi), RNE
__device__ __forceinline__ unsigned cvtpk(float lo, float hi){
  unsigned r;
  asm("v_cvt_pk_bf16_f32 %0, %1, %2" : "=v"(r) : "v"(lo), "v"(hi));
  return r;
}
__device__ __forceinline__ short8 mk8(unsigned a, unsigned b, unsigned c, unsigned d){
  union { uint4 u; short8 s; } t;
  t.u = make_uint4(a, b, c, d);
  return t.s;
}

__device__ __forceinline__ void init_body(int idx,
                       unsigned short* __restrict__ Tfb, unsigned short* __restrict__ Ts,
                       unsigned short* __restrict__ w1b, unsigned short* __restrict__ w2b,
                       unsigned short* __restrict__ pwb,
                       const float* __restrict__ fc1w, const float* __restrict__ fc2w,
                       const float* __restrict__ pw_w){
  if (idx < 32*288){                    // analysis twiddles: row 2k=cos, 2k+1=-sin
    int m = idx / 288, hc = idx % 288;
    unsigned short v = 0;
    if (m < 26 && hc < 265){
      int k = m >> 1;
      int t = (hc*k) % HP;
      float s, c; sincosf(TWO_PI*(float)t/(float)HP, &s, &c);
      v = f2b((m & 1) ? -s : c);
    }
    Tfb[idx] = v;
  }
  if (idx < 272*32){                    // synthesis twiddles (invN folded)
    int w = idx >> 5, kap = idx & 31;
    unsigned short v = 0;
    if (w < HP && kap < 24){
      int k = kap >> 1;
      int t = (w*k) % HP;
      float s, c; sincosf(TWO_PI*(float)t/(float)HP, &s, &c);
      const float invN = 1.f/70225.f;
      float val = (!(kap&1)) ? invN*(k==0 ? 1.f : 2.f*c)
                             : ((k==0) ? 0.f : -invN*2.f*s);
      v = f2b(val);
    }
    Ts[idx] = v;
  }
  if (idx < 4096){                      // w1b[n*32+s] = fc1w[pi(s)*128+n]
    int n = idx >> 5, s = idx & 31;     // pi: slot g*8+q -> ch (q<4 ? g*4+q : 16+g*4+q-4)
    int gg = s >> 3, q = s & 7;
    int ch = (q < 4) ? (gg*4 + q) : (16 + gg*4 + (q - 4));
    w1b[idx] = f2b(fc1w[ch*128 + n]);
  }
  if (idx < 2048){                      // w2b[n*128+k] = fc2w[k*3+n], n<3 else 0
    int n = idx >> 7, k = idx & 127;
    w2b[idx] = (n < 3) ? f2b(fc2w[k*3 + n]) : (unsigned short)0;
  }
  if (idx < 4096)                       // pwb = pw_w bf16
    pwb[idx] = f2b(pw_w[idx]);
}

// fc0 (3->32, bf16 channels-last, zero pad) + copy x_en/x_de + fused init tail
__global__ __launch_bounds__(256) void k_fc0(const float* __restrict__ xen,
                                             const float* __restrict__ w0,
                                             const float* __restrict__ b0,
                                             unsigned short* __restrict__ xb,
                                             float* __restrict__ out,
                                             unsigned short* __restrict__ Tfb,
                                             unsigned short* __restrict__ Ts,
                                             unsigned short* __restrict__ w1b,
                                             unsigned short* __restrict__ w2b,
                                             unsigned short* __restrict__ pwb,
                                             const float* __restrict__ fc1w,
                                             const float* __restrict__ fc2w,
                                             const float* __restrict__ pw_w){
  if (blockIdx.x >= 2195){
    init_body((blockIdx.x - 2195)*256 + threadIdx.x, Tfb, Ts, w1b, w2b, pwb,
              fc1w, fc2w, pw_w);
    return;
  }
  int idx = blockIdx.x*256 + threadIdx.x;
  if (idx >= 8*NPIX) return;
  int w = idx % HP; int t = idx / HP; int h = t % HP; int b = t / HP;
  float o32[32];
  if (h < 256 && w < 256){
    const float* xp = xen + (((size_t)b*3)*256 + h)*256 + w;
    float c0 = xp[0], c1 = xp[65536], c2 = xp[131072];
    #pragma unroll
    for (int d = 0; d < 32; ++d)
      o32[d] = b0[d] + c0*w0[d] + c1*w0[32+d] + c2*w0[64+d];
    size_t be = ((size_t)b*3)*65536 + (h<<8) + w;
    out[1769472 + be]          = c0;
    out[1769472 + be + 65536]  = c1;
    out[1769472 + be + 131072] = c2;
    if (((h|w)&3) == 0){
      size_t db = ((size_t)b*3)*4096 + ((h>>2)<<6) + (w>>2);
      out[98304 + db]        = c0;
      out[98304 + db + 4096] = c1;
      out[98304 + db + 8192] = c2;
    }
  } else {
    #pragma unroll
    for (int d = 0; d < 32; ++d) o32[d] = 0.f;
  }
  uint4* dst = (uint4*)(xb + (size_t)idx*32);
  #pragma unroll
  for (int q = 0; q < 4; ++q)
    dst[q] = make_uint4(cvtpk(o32[8*q],o32[8*q+1]),   cvtpk(o32[8*q+2],o32[8*q+3]),
                        cvtpk(o32[8*q+4],o32[8*q+5]), cvtpk(o32[8*q+6],o32[8*q+7]));
}

// MFMA h-DFT, LDS-free: U[b][m<26][n] = sum_h Tfb[m][h] * x[b][h][n]
__global__ __launch_bounds__(256) void k_dftm(const unsigned short* __restrict__ xb,
                                              const unsigned short* __restrict__ Tfb,
                                              float* __restrict__ U32){
  int tid = threadIdx.x;
  int wv = tid>>6, lane = tid&63, lr = lane&15, g = lane>>4, lk = g*8;
  int n0 = blockIdx.x*64;
  int b  = blockIdx.y;
  int n  = n0 + wv*16 + lr;
  const unsigned short* xcol = xb + (size_t)b*HP*ROWF + n;
  f32x4 acc0 = {0.f,0.f,0.f,0.f}, acc1 = {0.f,0.f,0.f,0.f};
  #pragma unroll
  for (int kc = 0; kc < 9; ++kc){
    short8 hv;
    int hb = kc*32 + lk;
    #pragma unroll
    for (int q = 0; q < 8; ++q){
      int h = hb + q;
      hv[q] = (h < HP) ? (short)xcol[(size_t)h*ROWF] : (short)0;
    }
    short8 aT0 = *(const short8*)&Tfb[lr*288 + kc*32 + lk];
    short8 aT1 = *(const short8*)&Tfb[(16+lr)*288 + kc*32 + lk];
    acc0 = __builtin_amdgcn_mfma_f32_16x16x32_bf16(aT0, hv, acc0, 0,0,0);
    acc1 = __builtin_amdgcn_mfma_f32_16x16x32_bf16(aT1, hv, acc1, 0,0,0);
  }
  if (n < 8480){
    #pragma unroll
    for (int r = 0; r < 4; ++r){
      int m0 = g*4 + r;
      U32[((size_t)b*26 + m0)*8480 + n] = acc0[r];
      int m1 = 16 + m0;
      if (m1 < 26) U32[((size_t)b*26 + m1)*8480 + n] = acc1[r];
    }
  }
}

// Column DFT + mode mix, one block per (j, b, ws); ws splits w-sweep in 4
__global__ __launch_bounds__(256) void k_spec(const float* __restrict__ U32,
                                              const float* __restrict__ w1r,
                                              const float* __restrict__ w1i,
                                              const float* __restrict__ w2r,
                                              const float* __restrict__ w2i,
                                              float2* __restrict__ G, int l){
  __shared__ float part[256*25];
  __shared__ float Xs[32*25];
  int j = blockIdx.x;
  int b = blockIdx.y;
  int ws = blockIdx.z;
  int tid = threadIdx.x;
  int wsub = tid >> 5, i = tid & 31;
  int kk   = (j < 12) ? j : (24 - j);
  bool cj  = (j >= 12);
  float xr[12], xi[12];
  #pragma unroll
  for (int k = 0; k < 12; ++k){ xr[k] = 0.f; xi[k] = 0.f; }
  const float* ubr = U32 + ((size_t)(b*26 + 2*kk))*8480;
  for (int w = ws*8 + wsub; w < HP; w += 32){
    int n = w*32 + i;
    float ux = ubr[n];
    float uy = ubr[8480 + n];
    if (cj) uy = -uy;
    float bs, bc; sincosf(-TWO_PI*(float)w/(float)HP, &bs, &bc);
    float pr = 1.f, pi = 0.f;
    #pragma unroll
    for (int k = 0; k < 12; ++k){
      xr[k] = fmaf(ux, pr, fmaf(-uy, pi, xr[k]));
      xi[k] = fmaf(ux, pi, fmaf( uy, pr, xi[k]));
      float npr = pr*bc - pi*bs;
      pi = fmaf(pr, bs, pi*bc);
      pr = npr;
    }
  }
  #pragma unroll
  for (int k = 0; k < 12; ++k){
    part[tid*25 + 2*k]     = xr[k];
    part[tid*25 + 2*k + 1] = xi[k];
  }
  __syncthreads();
  {
    int sg = tid >> 5;
    int ii = tid & 31;
    #pragma unroll
    for (int s0 = 0; s0 < 3; ++s0){
      int s = sg*3 + s0;
      float acc = 0.f;
      #pragma unroll
      for (int wq = 0; wq < 8; ++wq) acc += part[(wq*32 + ii)*25 + s];
      Xs[ii*25 + s] = acc;
    }
  }
  __syncthreads();
  int ky = (j < 12) ? j : (j - 12);
  const float* wr = (j < 12) ? w1r : w2r;
  const float* wi = (j < 12) ? w1i : w2i;
  float2* Gp = G + (size_t)ws*73728;
  for (int p = tid; p < 384; p += 256){
    int o = p / 12, kx = p % 12;
    size_t wbase = (size_t)l*147456 + (size_t)o*144 + (size_t)ky*12 + kx;
    float gr = 0.f, gi = 0.f;
    #pragma unroll 4
    for (int i2 = 0; i2 < 32; ++i2){
      float xvr = Xs[i2*25 + 2*kx];
      float xvi = Xs[i2*25 + 2*kx + 1];
      float a = wr[wbase + (size_t)i2*4608];
      float c = wi[wbase + (size_t)i2*4608];
      gr += xvr*a - xvi*c;
      gi += xvr*c + xvi*a;
    }
    Gp[((size_t)(b*32 + o)*24 + j)*12 + kx] = make_float2(gr, gi);
  }
}

// Inverse row synthesis (sums the 4 G partials); writes A as bf16 [b][h][o][32]
__global__ __launch_bounds__(320) void k_idft_h(const float2* __restrict__ G,
                                                unsigned short* __restrict__ A16){
  __shared__ float2 gs[288];
  int bo = blockIdx.x;
  for (int i = threadIdx.x; i < 288; i += 320){
    float2 g0 = G[(size_t)bo*288 + i];
    float2 g1 = G[73728 + (size_t)bo*288 + i];
    float2 g2 = G[2*73728 + (size_t)bo*288 + i];
    float2 g3 = G[3*73728 + (size_t)bo*288 + i];
    gs[i] = make_float2(g0.x+g1.x+g2.x+g3.x, g0.y+g1.y+g2.y+g3.y);
  }
  __syncthreads();
  if (threadIdx.x >= 133) return;
  int h = blockIdx.y*133 + threadIdx.x;
  if (h >= HP) return;
  float ar[12], ai[12];
  #pragma unroll
  for (int k = 0; k < 12; ++k){ ar[k] = 0.f; ai[k] = 0.f; }
  for (int j = 0; j < 24; ++j){
    int ky = (j < 12) ? j : (241 + j);
    int t = (ky*h) % HP;
    float s, c; sincosf(TWO_PI*(float)t/(float)HP, &s, &c);
    #pragma unroll
    for (int k = 0; k < 12; ++k){
      float2 g = gs[j*12 + k];
      ar[k] = fmaf(g.x, c, fmaf(-g.y, s, ar[k]));
      ai[k] = fmaf(g.x, s, fmaf( g.y, c, ai[k]));
    }
  }
  int b = bo >> 5, o = bo & 31;
  uint4* ap = (uint4*)(A16 + (((size_t)(b*HP + h))*32 + o)*32);
  #pragma unroll
  for (int q = 0; q < 3; ++q)
    ap[q] = make_uint4(cvtpk(ar[4*q],   ai[4*q]),   cvtpk(ar[4*q+1], ai[4*q+1]),
                       cvtpk(ar[4*q+2], ai[4*q+2]), cvtpk(ar[4*q+3], ai[4*q+3]));
  ap[3] = make_uint4(0u, 0u, 0u, 0u);
}

// MFMA final (layers 0..2), operand-swapped (D[o][w]), w-split over grid.z,
// manual prefetch of next tile's B-fragments.
__global__ __launch_bounds__(256) void k_final(const unsigned short* __restrict__ A16,
                                               const unsigned short* __restrict__ Tsyn,
                                               const unsigned short* __restrict__ pwb,
                                               const float* __restrict__ pw_b,
                                               unsigned short* __restrict__ xb, int l){
  int tid = threadIdx.x;
  int wv = tid>>6, lane = tid&63, lr = lane&15, g = lane>>4, lk = g*8;
  int h = blockIdx.x*4 + wv;
  int b = blockIdx.y;
  int z = blockIdx.z;
  if (h >= HP) return;
  const unsigned short* arow = A16 + (size_t)(b*HP + h)*1024;
  short8 aA0 = *(const short8*)&arow[lr*32 + lk];
  short8 aA1 = *(const short8*)&arow[(16+lr)*32 + lk];
  short8 aP0 = *(const short8*)&pwb[l*1024 + lr*32 + lk];
  short8 aP1 = *(const short8*)&pwb[l*1024 + (16+lr)*32 + lk];
  float4 vb0 = *(const float4*)&pw_b[l*32 + g*4];
  float4 vb1 = *(const float4*)&pw_b[l*32 + 16 + g*4];
  unsigned short* xrow = xb + (size_t)(b*HP + h)*ROWF;
  const f32x4 z4 = {0.f,0.f,0.f,0.f};
  const int wt0 = z ? 9 : 0, wt1 = z ? 17 : 9;
  int w = wt0*16 + lr;
  short8 bT = *(const short8*)&Tsyn[(size_t)w*32 + lk];
  short8 bX = *(const short8*)&xrow[(size_t)w*32 + lk];
  #pragma unroll
  for (int wt = wt0; wt < wt1; ++wt){
    short8 nT, nX;
    if (wt + 1 < wt1){
      int wn = (wt+1)*16 + lr;
      nT = *(const short8*)&Tsyn[(size_t)wn*32 + lk];
      nX = *(const short8*)&xrow[(size_t)wn*32 + lk];
    }
    f32x4 a0 = __builtin_amdgcn_mfma_f32_16x16x32_bf16(aA0, bT, z4, 0,0,0);
    a0 = __builtin_amdgcn_mfma_f32_16x16x32_bf16(aP0, bX, a0, 0,0,0);
    f32x4 a1 = __builtin_amdgcn_mfma_f32_16x16x32_bf16(aA1, bT, z4, 0,0,0);
    a1 = __builtin_amdgcn_mfma_f32_16x16x32_bf16(aP1, bX, a1, 0,0,0);
    if (w < HP){
      float v0[4], v1[4];
      v0[0]=a0[0]+vb0.x; v0[1]=a0[1]+vb0.y; v0[2]=a0[2]+vb0.z; v0[3]=a0[3]+vb0.w;
      v1[0]=a1[0]+vb1.x; v1[1]=a1[1]+vb1.y; v1[2]=a1[2]+vb1.z; v1[3]=a1[3]+vb1.w;
      #pragma unroll
      for (int r = 0; r < 4; ++r){ v0[r] = gelu_f(v0[r]); v1[r] = gelu_f(v1[r]); }
      *(uint2*)&xrow[(size_t)w*32 + g*4] =
          make_uint2(cvtpk(v0[0],v0[1]), cvtpk(v0[2],v0[3]));
      *(uint2*)&xrow[(size_t)w*32 + 16 + g*4] =
          make_uint2(cvtpk(v1[0],v1[1]), cvtpk(v1[2],v1[3]));
    }
    bT = nT; bX = nX; w += 16;
  }
}

// Fused last layer + head: synth+pw (no gelu) -> registers -> fc1 MFMA
// (pi-permuted weights consume the register layout directly) -> gelu ->
// LDS P -> fc2 MFMA -> +x_en -> out. Never touches xb for writes.
// Grid: (64, 8, 2); wave = one h-row (0..255), 8 w-tiles per wave.
__global__ __launch_bounds__(256) void k_last(const unsigned short* __restrict__ A16,
                                              const unsigned short* __restrict__ Tsyn,
                                              const unsigned short* __restrict__ pwb,
                                              const float* __restrict__ pw_b,
                                              const unsigned short* __restrict__ xb,
                                              const float* __restrict__ xen,
                                              const unsigned short* __restrict__ w1bp,
                                              const float* __restrict__ fc1b,
                                              const unsigned short* __restrict__ w2b,
                                              const float* __restrict__ fc2b,
                                              float* __restrict__ out){
  __shared__ unsigned short Pm[4][16*136];
  int tid = threadIdx.x;
  int wv = tid>>6, lane = tid&63, lr = lane&15, g = lane>>4, lk = g*8;
  int h = blockIdx.x*4 + wv;     // 0..255
  int b = blockIdx.y;
  int z = blockIdx.z;            // w-tile half
  const int l = 3;
  const unsigned short* arow = A16 + (size_t)(b*HP + h)*1024;
  short8 aA0 = *(const short8*)&arow[lr*32 + lk];
  short8 aA1 = *(const short8*)&arow[(16+lr)*32 + lk];
  short8 aP0 = *(const short8*)&pwb[l*1024 + lr*32 + lk];
  short8 aP1 = *(const short8*)&pwb[l*1024 + (16+lr)*32 + lk];
  float4 vb0 = *(const float4*)&pw_b[l*32 + g*4];
  float4 vb1 = *(const float4*)&pw_b[l*32 + 16 + g*4];
  short8 bf1[8], bf2[4];
  #pragma unroll
  for (int nt = 0; nt < 8; ++nt)
    bf1[nt] = *(const short8*)&w1bp[(nt*16+lr)*32 + lk];
  #pragma unroll
  for (int ks = 0; ks < 4; ++ks)
    bf2[ks] = *(const short8*)&w2b[lr*128 + ks*32 + lk];
  float f2c = (lr < 3) ? fc2b[lr] : 0.f;
  const unsigned short* xrow = xb + (size_t)(b*HP + h)*ROWF;
  unsigned short* P = Pm[wv];
  const f32x4 z4 = {0.f,0.f,0.f,0.f};
  for (int wt = z*8; wt < z*8 + 8; ++wt){
    int w0 = wt*16;
    int w = w0 + lr;
    short8 bT = *(const short8*)&Tsyn[(size_t)w*32 + lk];
    short8 bX = *(const short8*)&xrow[(size_t)w*32 + lk];
    f32x4 a0 = __builtin_amdgcn_mfma_f32_16x16x32_bf16(aA0, bT, z4, 0,0,0);
    a0 = __builtin_amdgcn_mfma_f32_16x16x32_bf16(aP0, bX, a0, 0,0,0);
    f32x4 a1 = __builtin_amdgcn_mfma_f32_16x16x32_bf16(aA1, bT, z4, 0,0,0);
    a1 = __builtin_amdgcn_mfma_f32_16x16x32_bf16(aP1, bX, a1, 0,0,0);
    // x values (last layer: no activation), packed to fc1 B-frag in pi-order
    float v0[4], v1[4];
    v0[0]=a0[0]+vb0.x; v0[1]=a0[1]+vb0.y; v0[2]=a0[2]+vb0.z; v0[3]=a0[3]+vb0.w;
    v1[0]=a1[0]+vb1.x; v1[1]=a1[1]+vb1.y; v1[2]=a1[2]+vb1.z; v1[3]=a1[3]+vb1.w;
    short8 xf = mk8(cvtpk(v0[0],v0[1]), cvtpk(v0[2],v0[3]),
                    cvtpk(v1[0],v1[1]), cvtpk(v1[2],v1[3]));
    f32x4 acc[8];
    #pragma unroll
    for (int nt = 0; nt < 8; ++nt)
      acc[nt] = __builtin_amdgcn_mfma_f32_16x16x32_bf16(bf1[nt], xf, z4, 0,0,0);
    #pragma unroll
    for (int nt = 0; nt < 8; ++nt){
      float4 bb = *(const float4*)&fc1b[nt*16 + g*4];
      float h0 = gelu_f(acc[nt][0] + bb.x);
      float h1 = gelu_f(acc[nt][1] + bb.y);
      float h2 = gelu_f(acc[nt][2] + bb.z);
      float h3 = gelu_f(acc[nt][3] + bb.w);
      *(uint2*)&P[lr*136 + nt*16 + g*4] =
          make_uint2(cvtpk(h0,h1), cvtpk(h2,h3));
    }
    f32x4 a2 = z4;
    #pragma unroll
    for (int ks = 0; ks < 4; ++ks){
      short8 ap = *(const short8*)&P[lr*136 + ks*32 + lk];
      a2 = __builtin_amdgcn_mfma_f32_16x16x32_bf16(ap, bf2[ks], a2, 0,0,0);
    }
    if (lr < 3){
      size_t base = ((size_t)(b*3 + lr))*65536 + (h<<8) + w0 + g*4;
      float4 xe = *(const float4*)&xen[base];
      float4 pr;
      pr.x = a2[0] + f2c + xe.x;
      pr.y = a2[1] + f2c + xe.y;
      pr.z = a2[2] + f2c + xe.z;
      pr.w = a2[3] + f2c + xe.w;
      *(float4*)&out[196608 + base] = pr;
      if ((h & 3) == 0){
        int w4 = (w0 + g*4) >> 2;
        out[((size_t)(b*3 + lr))*4096 + ((h>>2)<<6) + w4] = pr.x;
      }
    }
  }
}

extern "C" void kernel_launch(void* const* d_in, const int* in_sizes, int n_in,
                              void* d_out, int out_size, void* d_ws, size_t ws_size,
                              hipStream_t stream){
  const float* x_en  = (const float*)d_in[0];
  const float* fc0_w = (const float*)d_in[2];
  const float* fc0_b = (const float*)d_in[3];
  const float* w1r   = (const float*)d_in[4];
  const float* w1i   = (const float*)d_in[5];
  const float* w2r   = (const float*)d_in[6];
  const float* w2i   = (const float*)d_in[7];
  const float* pw_w  = (const float*)d_in[8];
  const float* pw_b  = (const float*)d_in[9];
  const float* fc1_w = (const float*)d_in[10];
  const float* fc1_b = (const float*)d_in[11];
  const float* fc2_w = (const float*)d_in[12];
  const float* fc2_b = (const float*)d_in[13];
  float* out = (float*)d_out;
  float* ws  = (float*)d_ws;

  unsigned short* xb  = (unsigned short*)(ws + OFF_X);
  float*  U32         = ws + OFF_U;
  float2* G           = (float2*)(ws + OFF_G);
  unsigned short* A16 = (unsigned short*)(ws + OFF_A);
  unsigned short* Tfb = (unsigned short*)(ws + OFF_TFB);
  unsigned short* Ts  = (unsigned short*)(ws + OFF_TS);
  unsigned short* w1b = (unsigned short*)(ws + OFF_W1B);
  unsigned short* w2b = (unsigned short*)(ws + OFF_W2B);
  unsigned short* pwb = (unsigned short*)(ws + OFF_PWB);

  k_fc0<<<2231, 256, 0, stream>>>(x_en, fc0_w, fc0_b, xb, out,
                                  Tfb, Ts, w1b, w2b, pwb, fc1_w, fc2_w, pw_w);
  for (int l = 0; l < 4; ++l){
    k_dftm<<<dim3(133,8), 256, 0, stream>>>(xb, Tfb, U32);
    k_spec<<<dim3(24,8,4), 256, 0, stream>>>(U32, w1r, w1i, w2r, w2i, G, l);
    k_idft_h<<<dim3(256,2), 320, 0, stream>>>(G, A16);
    if (l < 3)
      k_final<<<dim3(67,8,2), 256, 0, stream>>>(A16, Ts, pwb, pw_b, xb, l);
  }
  k_last<<<dim3(64,8,2), 256, 0, stream>>>(A16, Ts, pwb, pw_b, xb, x_en,
                                           w1b, fc1_b, w2b, fc2_b, out);
}